// Round 13
// baseline (84.180 us; speedup 1.0000x reference)
//
#include <hip/hip_runtime.h>
#include <hip/hip_bf16.h>

#define NB 4
#define NQ 512
#define NK 2048
#define ND 256
#define NH 64
#define QT 4                      // queries per attn block
#define KSPLIT 4

#define SCALE_C 2.8853900817779268f   // 2*log2(e): u = exp2(-|C(q+k)|) = e^{-2|q+k|}
#define L2E     1.4426950408889634f

// minimax deg-4 of 1/(1+u) on [0,1] (Chebyshev-derived, |err| ~ 3e-4)
#define PC0  0.99960f
#define PC1 -0.98603f
#define PC2  0.87200f
#define PC3 -0.54233f
#define PC4  0.15688f

typedef float f2 __attribute__((ext_vector_type(2)));

__device__ __forceinline__ unsigned short f2b(float f) {   // f32 -> bf16 (RNE)
    unsigned u = __float_as_uint(f);
    u += 0x7fffu + ((u >> 16) & 1u);
    return (unsigned short)(u >> 16);
}
__device__ __forceinline__ float b2f_lo(unsigned u) { return __uint_as_float(u << 16); }
__device__ __forceinline__ float b2f_hi(unsigned u) { return __uint_as_float(u & 0xffff0000u); }

__device__ __forceinline__ float wred_sum(float v) {
#pragma unroll
    for (int off = 32; off; off >>= 1) v += __shfl_xor(v, off, 64);
    return v;
}

// score-accumulate 2 elements (a q-pair at one h): s += wv * tanh(y), packed
__device__ __forceinline__ void proc2(f2 q2, f2 k2, float wvh, f2& s) {
    f2 y = q2 + k2;                                        // v_pk_add_f32
    unsigned sx = __float_as_uint(y.x) & 0x80000000u;
    unsigned sy = __float_as_uint(y.y) & 0x80000000u;
    f2 u;
    u.x = __builtin_amdgcn_exp2f(-__builtin_fabsf(y.x));   // 1 trans, -|.| = src mods
    u.y = __builtin_amdgcn_exp2f(-__builtin_fabsf(y.y));
    f2 p = __builtin_elementwise_fma(u, (f2)(PC4), (f2)(PC3));
    p = __builtin_elementwise_fma(p, u, (f2)(PC2));
    p = __builtin_elementwise_fma(p, u, (f2)(PC1));
    p = __builtin_elementwise_fma(p, u, (f2)(PC0));
    f2 t = u * p;                                          // v_pk_mul_f32
    f2 r = __builtin_elementwise_fma(t, (f2)(-2.0f), (f2)(1.0f));  // 1-2uP = |tanh|
    unsigned wu = __float_as_uint(wvh);
    f2 wvs;
    wvs.x = __uint_as_float(wu ^ sx);                      // wv * sign(y)
    wvs.y = __uint_as_float(wu ^ sy);
    s = __builtin_elementwise_fma(wvs, r, s);              // v_pk_fma_f32
}

// ---------- kernel A: projections, pre-scaled by 2*log2(e) ----------
// queries -> qp[b*NQ+q][h] (row-major); keys -> kpT[b][h][k] (TRANSPOSED)
__global__ __launch_bounds__(256) void proj_kernel(
    const float* __restrict__ queries, const float* __restrict__ keys,
    const float* __restrict__ Wq, const float* __restrict__ Wk,
    float* __restrict__ qp, float* __restrict__ kpT)
{
    __shared__ __align__(16) float in_lds[16][256];
    const int t = threadIdx.x;
    const int row0 = blockIdx.x * 16;
    const bool isQ = row0 < NB * NQ;
    const float* src = isQ ? (queries + (size_t)row0 * ND)
                           : (keys + (size_t)(row0 - NB * NQ) * ND);
    const float* W = isQ ? Wq : Wk;

    const float4* src4 = (const float4*)src;
#pragma unroll
    for (int i = 0; i < 4; ++i) {
        int f4 = t + 256 * i;
        ((float4*)&in_lds[0][0])[f4] = src4[f4];
    }
    __syncthreads();

    const int w = t >> 6, h = t & 63;
    const int r0 = w * 4;
    float a[4] = {0.f, 0.f, 0.f, 0.f};
#pragma unroll 4
    for (int d4 = 0; d4 < 64; ++d4) {
        const float* Wp = W + (size_t)(d4 * 4) * NH + h;
        float w0 = Wp[0], w1 = Wp[NH], w2 = Wp[2 * NH], w3 = Wp[3 * NH];
#pragma unroll
        for (int i = 0; i < 4; ++i) {
            float4 x = ((const float4*)in_lds[r0 + i])[d4];
            a[i] = fmaf(x.x, w0, fmaf(x.y, w1, fmaf(x.z, w2, fmaf(x.w, w3, a[i]))));
        }
    }
    if (isQ) {
#pragma unroll
        for (int i = 0; i < 4; ++i)
            qp[(size_t)(row0 + r0 + i) * NH + h] = a[i] * SCALE_C;
    } else {
#pragma unroll
        for (int i = 0; i < 4; ++i) {
            int kr = row0 - NB * NQ + r0 + i;         // global key row
            int b = kr >> 11, k = kr & (NK - 1);
            kpT[((size_t)((b << 6) + h)) * NK + k] = a[i] * SCALE_C;  // scattered, tiny
        }
    }
}

// ---------- kernel B: partial scores + no-max softmax + partial PV ----------
// grid = NB*(NQ/QT)*KSPLIT = 2048 blocks, 256 threads (4 waves), 8 blocks/CU.
// Block decode (diagonal batch<->split pairing): sp = n&3, qg = n>>2,
//   b = ((qg>>7)+sp)&3, qt = qg&127.
// Balanced dynamic split (R8 formula): range <= 512, multiple of 8.
// Score inner loop: tanh via u=exp2(-|y|) + deg-4 poly (1 trans/elem), q-pairs
// packed as float2 ext-vectors so LLVM can emit v_pk_* (2 elem/instr).
__global__ __launch_bounds__(256, 8) void attn_part(
    const float* __restrict__ values, const int* __restrict__ valid_lens,
    const float* __restrict__ wv,
    const float* __restrict__ qp, const float* __restrict__ kpT,
    float* __restrict__ po, float* __restrict__ pml)
{
    // 8 KB union:
    //   phase 1-2: [0..1024) = p_l ushort[512][4] bf16; [1024..1280) = qpi float4[64]
    //   phase 3  : [0..2048) = red, 2 slots x 1024 f32 (4q x 256d)
    __shared__ __align__(16) float smem[2048];
    __shared__ __align__(16) float wv_l[NH];
    __shared__ float red_l[QT][4];

    unsigned short* p_l = (unsigned short*)smem;      // p_l[kl*4 + q], bf16
    float4* qpi = (float4*)(smem + 1024);             // qpi[hp*2+pp] = {q(2pp,2hp), q(2pp+1,2hp), q(2pp,2hp+1), q(2pp+1,2hp+1)}
    float* red  = smem;

    const int t = threadIdx.x;
    const int n = blockIdx.x;
    const int sp = n & 3;
    const int qg = n >> 2;                            // 0..511
    const int b  = ((qg >> 7) + sp) & 3;
    const int qt = qg & 127;
    const int q0 = qt * QT;
    const int wid = t >> 6;                           // 0..3
    const int dl = (t & 63) * 4;

    if (t < 64) {
        // interleaved qp tile: thread t -> (hp = t>>1, pp = t&1)
        const int hp = t >> 1, pp = t & 1;
        const float* qr = qp + (size_t)(b * NQ + q0) * NH;
        float4 v;
        v.x = qr[(2 * pp + 0) * NH + 2 * hp];
        v.y = qr[(2 * pp + 1) * NH + 2 * hp];
        v.z = qr[(2 * pp + 0) * NH + 2 * hp + 1];
        v.w = qr[(2 * pp + 1) * NH + 2 * hp + 1];
        qpi[t] = v;
    }
    if (t >= 64 && t < 128) {
        int h = t - 64;
        wv_l[h] = wv[h];
    }
    int vl = valid_lens[b];
    const int kv = vl < 0 ? 0 : (vl > NK ? NK : vl);
    const int kveff = (kv == 0) ? NK : kv;    // kv==0 -> uniform over all keys
    // balanced bounds, range always multiple of 8 and <= 512
    const int step   = ((kveff + 31) & ~31) >> 2;        // ceil(kveff/4) to mult-of-8
    const int kvr8   = (kveff + 7) & ~7;
    const int kstart = sp * step;
    int kend = kstart + step; if (kend > kvr8) kend = kvr8;
    const int range8 = (kend > kstart) ? (kend - kstart) : 0;   // <= 512
    __syncthreads();

    // ---- phase 1: e-values (bf16) into p_l; 4 q per thread (2 f2 pairs), 2 k-slots ----
    {
        float sum_q[4] = {0.f, 0.f, 0.f, 0.f};
#pragma unroll
        for (int slot = 0; slot < 2; ++slot) {
            const int klocal = t + slot * 256;
            if (klocal < range8) {
                const int kg = kstart + klocal;
                float e[4];
                if (kv == 0) {
#pragma unroll
                    for (int j = 0; j < 4; ++j) e[j] = 1.0f;
                } else if (kg < kv) {
                    f2 s2[2];
                    s2[0] = (f2)(0.f); s2[1] = (f2)(0.f);
                    const float* kT = kpT + ((size_t)(b << 6)) * NK + kg;  // coalesced
#pragma unroll
                    for (int hb = 0; hb < 8; ++hb) {
                        float kh[8];
#pragma unroll
                        for (int i = 0; i < 8; ++i) kh[i] = kT[(size_t)(hb * 8 + i) * NK];
#pragma unroll
                        for (int m = 0; m < 4; ++m) {          // h-pair within hb
                            const int hp = hb * 4 + m;
                            f2 wvp = ((const f2*)wv_l)[hp];    // (wv[2hp], wv[2hp+1])
                            f2 kk0; kk0.x = kh[2 * m];     kk0.y = kh[2 * m];
                            f2 kk1; kk1.x = kh[2 * m + 1]; kk1.y = kh[2 * m + 1];
#pragma unroll
                            for (int pp = 0; pp < 2; ++pp) {
                                float4 fq = qpi[hp * 2 + pp];  // LDS broadcast b128
                                f2 a; a.x = fq.x; a.y = fq.y;  // q-pair @ h=2hp
                                f2 c; c.x = fq.z; c.y = fq.w;  // q-pair @ h=2hp+1
                                proc2(a, kk0, wvp.x, s2[pp]);
                                proc2(c, kk1, wvp.y, s2[pp]);
                            }
                        }
                    }
                    e[0] = __builtin_amdgcn_exp2f(s2[0].x * L2E);
                    e[1] = __builtin_amdgcn_exp2f(s2[0].y * L2E);
                    e[2] = __builtin_amdgcn_exp2f(s2[1].x * L2E);
                    e[3] = __builtin_amdgcn_exp2f(s2[1].y * L2E);
                } else {
#pragma unroll
                    for (int j = 0; j < 4; ++j) e[j] = 0.f;
                }
                // pack to bf16; sums use rounded values so l matches PV exactly
                unsigned eb[4];
#pragma unroll
                for (int j = 0; j < 4; ++j) {
                    eb[j] = (unsigned)f2b(e[j]);
                    sum_q[j] += b2f_lo(eb[j]);
                }
                uint2 u;
                u.x = eb[0] | (eb[1] << 16);
                u.y = eb[2] | (eb[3] << 16);
                *(uint2*)&p_l[(size_t)klocal * 4] = u;
            }
        }
#pragma unroll
        for (int j = 0; j < 4; ++j) {
            float s = wred_sum(sum_q[j]);
            if ((t & 63) == 0) red_l[j][wid] = s;
        }
    }
    __syncthreads();

    // ---- phase 2: PV, waves split k (row kl handled by wave kl%4) ----
    float4 acc[QT];
#pragma unroll
    for (int q = 0; q < QT; ++q) acc[q] = make_float4(0.f, 0.f, 0.f, 0.f);

    const float* Vb = values + ((size_t)b * NK + kstart) * ND;
#pragma unroll 2
    for (int kl = wid; kl < range8; kl += 4) {
        uint2 u = *(const uint2*)&p_l[(size_t)kl * 4];   // 1 b64 = all 4 bf16 p's
        float pr0 = b2f_lo(u.x), pr1 = b2f_hi(u.x);
        float pr2 = b2f_lo(u.y), pr3 = b2f_hi(u.y);
        float4 v = *(const float4*)(Vb + (size_t)kl * ND + dl);  // coalesced 1KB
        acc[0].x = fmaf(pr0, v.x, acc[0].x); acc[0].y = fmaf(pr0, v.y, acc[0].y);
        acc[0].z = fmaf(pr0, v.z, acc[0].z); acc[0].w = fmaf(pr0, v.w, acc[0].w);
        acc[1].x = fmaf(pr1, v.x, acc[1].x); acc[1].y = fmaf(pr1, v.y, acc[1].y);
        acc[1].z = fmaf(pr1, v.z, acc[1].z); acc[1].w = fmaf(pr1, v.w, acc[1].w);
        acc[2].x = fmaf(pr2, v.x, acc[2].x); acc[2].y = fmaf(pr2, v.y, acc[2].y);
        acc[2].z = fmaf(pr2, v.z, acc[2].z); acc[2].w = fmaf(pr2, v.w, acc[2].w);
        acc[3].x = fmaf(pr3, v.x, acc[3].x); acc[3].y = fmaf(pr3, v.y, acc[3].y);
        acc[3].z = fmaf(pr3, v.z, acc[3].z); acc[3].w = fmaf(pr3, v.w, acc[3].w);
    }
    __syncthreads();                          // p/qpi dead -> reuse smem as scratch

    // ---- phase 3: tree-reduce partials across waves (4 -> 2 -> 1) ----
    if (wid >= 2) {
        float* s = red + (size_t)(wid - 2) * 1024;
#pragma unroll
        for (int q = 0; q < QT; ++q) *(float4*)(s + q * 256 + dl) = acc[q];
    }
    __syncthreads();
    if (wid < 2) {
        const float* s = red + (size_t)wid * 1024;
#pragma unroll
        for (int q = 0; q < QT; ++q) {
            float4 r = *(const float4*)(s + q * 256 + dl);
            acc[q].x += r.x; acc[q].y += r.y; acc[q].z += r.z; acc[q].w += r.w;
        }
    }
    __syncthreads();
    if (wid == 1) {
#pragma unroll
        for (int q = 0; q < QT; ++q) *(float4*)(red + q * 256 + dl) = acc[q];
    }
    __syncthreads();
    if (wid == 0) {
#pragma unroll
        for (int q = 0; q < QT; ++q) {
            float4 r = *(const float4*)(red + q * 256 + dl);
            acc[q].x += r.x; acc[q].y += r.y; acc[q].z += r.z; acc[q].w += r.w;
            const size_t row4 = ((size_t)(b * NQ + q0 + q) * KSPLIT + sp);
            *(float4*)(po + row4 * ND + dl) = acc[q];
        }
        if (t < QT) {
            float l = red_l[t][0] + red_l[t][1] + red_l[t][2] + red_l[t][3];
            pml[((size_t)(b * NQ + q0 + t) * KSPLIT + sp)] = l;
        }
    }
}

// ---------- kernel C: combine the four splits ----------
__global__ __launch_bounds__(256) void combine_kernel(
    const float* __restrict__ po, const float* __restrict__ pml,
    float* __restrict__ out)
{
    const int t = threadIdx.x;
    const int row = blockIdx.x * 4 + (t >> 6);
    const int dl = (t & 63) * 4;
    float l = 0.f;
#pragma unroll
    for (int s = 0; s < KSPLIT; ++s) l += pml[row * KSPLIT + s];
    float4 o = make_float4(0.f, 0.f, 0.f, 0.f);
#pragma unroll
    for (int s = 0; s < KSPLIT; ++s) {
        float4 p = *(const float4*)(po + ((size_t)row * KSPLIT + s) * ND + dl);
        o.x += p.x; o.y += p.y; o.z += p.z; o.w += p.w;
    }
    const float inv = 1.0f / l;
    o.x *= inv; o.y *= inv; o.z *= inv; o.w *= inv;
    *(float4*)(out + (size_t)row * ND + dl) = o;
}

extern "C" void kernel_launch(void* const* d_in, const int* in_sizes, int n_in,
                              void* d_out, int out_size, void* d_ws, size_t ws_size,
                              hipStream_t stream) {
    const float* queries   = (const float*)d_in[0];
    const float* keys      = (const float*)d_in[1];
    const float* values    = (const float*)d_in[2];
    const int* valid_lens  = (const int*)d_in[3];
    const float* Wq        = (const float*)d_in[4];
    const float* Wk        = (const float*)d_in[5];
    const float* wv        = (const float*)d_in[6];
    float* out = (float*)d_out;

    float* qp  = (float*)d_ws;                          // NB*NQ*NH      (0.5 MB)
    float* kpT = qp + (size_t)NB * NQ * NH;             // NB*NH*NK      (2 MB)
    float* po  = kpT + (size_t)NB * NH * NK;            // NB*NQ*4*ND    (8 MB)
    float* pml = po + (size_t)NB * NQ * KSPLIT * ND;    // NB*NQ*4

    proj_kernel<<<(NB * NQ + NB * NK) / 16, 256, 0, stream>>>(queries, keys, Wq, Wk, qp, kpT);
    attn_part<<<NB * (NQ / QT) * KSPLIT, 256, 0, stream>>>(values, valid_lens, wv, qp, kpT, po, pml);
    combine_kernel<<<NB * NQ / 4, 256, 0, stream>>>(po, pml, out);
}

// Round 14
// 76.902 us; speedup vs baseline: 1.0946x; 1.0946x over previous
//
#include <hip/hip_runtime.h>
#include <hip/hip_bf16.h>

#define NB 4
#define NQ 512
#define NK 2048
#define ND 256
#define NH 64
#define QT 8                      // queries per attn block
#define KSPLIT 4

#define SCALE_C 2.8853900817779268f   // 2*log2(e): exp2(C*(q+k)) = e^{2(q+k)}
#define L2E     1.4426950408889634f

__device__ __forceinline__ unsigned short f2b(float f) {   // f32 -> bf16 (RNE)
    unsigned u = __float_as_uint(f);
    u += 0x7fffu + ((u >> 16) & 1u);
    return (unsigned short)(u >> 16);
}
__device__ __forceinline__ float b2f_lo(unsigned u) { return __uint_as_float(u << 16); }
__device__ __forceinline__ float b2f_hi(unsigned u) { return __uint_as_float(u & 0xffff0000u); }

__device__ __forceinline__ float wred_sum(float v) {
#pragma unroll
    for (int off = 32; off; off >>= 1) v += __shfl_xor(v, off, 64);
    return v;
}

// ---------- kernel A: projections, pre-scaled by 2*log2(e) ----------
// queries -> qp[b*NQ+q][h] (row-major)
// keys    -> kp4[(b*16 + h/4)*NK + k] : float4 of h-quad (h-grouped, k-fast)
__global__ __launch_bounds__(256) void proj_kernel(
    const float* __restrict__ queries, const float* __restrict__ keys,
    const float* __restrict__ Wq, const float* __restrict__ Wk,
    float* __restrict__ qp, float4* __restrict__ kp4)
{
    __shared__ __align__(16) float in_lds[16][256];   // 16 KB; reused as [16][64] out
    const int t = threadIdx.x;
    const int row0 = blockIdx.x * 16;
    const bool isQ = row0 < NB * NQ;                  // blocks are purely Q or purely K
    const float* src = isQ ? (queries + (size_t)row0 * ND)
                           : (keys + (size_t)(row0 - NB * NQ) * ND);
    const float* W = isQ ? Wq : Wk;

    const float4* src4 = (const float4*)src;
#pragma unroll
    for (int i = 0; i < 4; ++i) {
        int f4 = t + 256 * i;
        ((float4*)&in_lds[0][0])[f4] = src4[f4];
    }
    __syncthreads();

    const int w = t >> 6, h = t & 63;
    const int r0 = w * 4;
    float a[4] = {0.f, 0.f, 0.f, 0.f};
#pragma unroll 4
    for (int d4 = 0; d4 < 64; ++d4) {
        const float* Wp = W + (size_t)(d4 * 4) * NH + h;
        float w0 = Wp[0], w1 = Wp[NH], w2 = Wp[2 * NH], w3 = Wp[3 * NH];
#pragma unroll
        for (int i = 0; i < 4; ++i) {
            float4 x = ((const float4*)in_lds[r0 + i])[d4];
            a[i] = fmaf(x.x, w0, fmaf(x.y, w1, fmaf(x.z, w2, fmaf(x.w, w3, a[i]))));
        }
    }
    if (isQ) {
#pragma unroll
        for (int i = 0; i < 4; ++i)
            qp[(size_t)(row0 + r0 + i) * NH + h] = a[i] * SCALE_C;
    } else {
        // transpose through LDS to emit h-quads per key
        __syncthreads();                              // in_lds reads complete
        float* out2 = &in_lds[0][0];                  // [16][64]
#pragma unroll
        for (int i = 0; i < 4; ++i)
            out2[(r0 + i) * 64 + h] = a[i] * SCALE_C;
        __syncthreads();
        const int row = t >> 4, hb = t & 15;          // 16 rows x 16 h-quads
        float4 v = *(const float4*)&out2[row * 64 + hb * 4];
        int kr = row0 - NB * NQ + row;
        int b = kr >> 11, k = kr & (NK - 1);
        kp4[((size_t)(b * 16 + hb)) * NK + k] = v;
    }
}

// ---------- kernel B: partial scores + no-max softmax + partial PV ----------
// grid = NB*(NQ/QT)*KSPLIT = 1024 blocks, 512 threads (8 waves).
// Block decode (diagonal batch<->split pairing): g = n&255, sp = n>>8,
//   b = ((g>>6)+sp)&3, qt = g&63.
// Balanced dynamic split (R8 formula): range <= 512, multiple of 8; phase 1
// is straight-line one-k-per-thread (no spill). kp read as h-quad float4:
// 16 dwordx4 loads per k (was 64 dword), batched 4-in-flight.
__global__ __launch_bounds__(512, 8) void attn_part(
    const float* __restrict__ values, const int* __restrict__ valid_lens,
    const float* __restrict__ wv,
    const float* __restrict__ qp, const float4* __restrict__ kp4,
    float* __restrict__ po, float* __restrict__ pml)
{
    __shared__ __align__(16) float qp_l[QT][NH];      // 2 KB (LDS broadcast source)
    __shared__ __align__(16) float wv2_l[NH];         // -2*wv
    __shared__ float sumwv_l;
    __shared__ __align__(16) float buf[8192];         // 32 KB: p bf16 (8KB) / red scratch
    __shared__ float red_l[QT][8];

    unsigned short* p_l = (unsigned short*)buf;       // p_l[kl*8 + q], bf16

    const int t = threadIdx.x;
    const int n = blockIdx.x;
    const int g = n & 255;
    const int sp = n >> 8;
    const int b  = ((g >> 6) + sp) & 3;
    const int qt = g & 63;
    const int q0 = qt * QT;
    const int wid = t >> 6;
    const int dl = (t & 63) * 4;

    if (t < 128) {
        int q = t >> 4, h4 = t & 15;
        ((float4*)qp_l[q])[h4] =
            ((const float4*)(qp + (size_t)(b * NQ + q0 + q) * NH))[h4];
    }
    if (t < 64) {
        float wvv = wv[t];
        wv2_l[t] = -2.0f * wvv;
        float s = wred_sum(wvv);
        if (t == 0) sumwv_l = s;
    }
    int vl = valid_lens[b];
    const int kv = vl < 0 ? 0 : (vl > NK ? NK : vl);
    const int kveff = (kv == 0) ? NK : kv;    // kv==0 -> uniform over all keys
    // balanced bounds, range always multiple of 8 and <= 512
    const int step   = ((kveff + 31) & ~31) >> 2;        // ceil(kveff/4) to mult-of-8
    const int kvr8   = (kveff + 7) & ~7;
    const int kstart = sp * step;
    int kend = kstart + step; if (kend > kvr8) kend = kvr8;
    const int range8 = (kend > kstart) ? (kend - kstart) : 0;   // <= 512
    __syncthreads();
    const float sumwv = sumwv_l;

    // ---- phase 1: e-values (bf16) into p_l, ONE k per thread ----
    {
        const int kl = t;
        float sum_q[QT];
#pragma unroll
        for (int q = 0; q < QT; ++q) sum_q[q] = 0.f;
        if (kl < range8) {
            const int kg = kstart + kl;
            float e[QT];
            if (kv == 0) {
#pragma unroll
                for (int q = 0; q < QT; ++q) e[q] = 1.0f;
            } else if (kg < kv) {
                float s[QT];
#pragma unroll
                for (int q = 0; q < QT; ++q) s[q] = sumwv;
                const float4* kT4 = kp4 + (size_t)(b * 16) * NK + kg;  // h-quad stride NK
#pragma unroll
                for (int gq = 0; gq < 4; ++gq) {      // 4 batches of 4 h-quads
                    float4 kb[4];                     // 4 dwordx4 in flight
#pragma unroll
                    for (int i = 0; i < 4; ++i)
                        kb[i] = kT4[(size_t)(gq * 4 + i) * NK];
#pragma unroll
                    for (int i = 0; i < 4; ++i) {
                        const int h4 = gq * 4 + i;
                        float4 w4 = ((const float4*)wv2_l)[h4];
                        float4 kh = kb[i];
#pragma unroll
                        for (int q = 0; q < QT; ++q) {
                            float4 qh = ((const float4*)qp_l[q])[h4];   // LDS broadcast
                            float r0 = __builtin_amdgcn_rcpf(__builtin_amdgcn_exp2f(qh.x + kh.x) + 1.0f);
                            float r1 = __builtin_amdgcn_rcpf(__builtin_amdgcn_exp2f(qh.y + kh.y) + 1.0f);
                            float r2 = __builtin_amdgcn_rcpf(__builtin_amdgcn_exp2f(qh.z + kh.z) + 1.0f);
                            float r3 = __builtin_amdgcn_rcpf(__builtin_amdgcn_exp2f(qh.w + kh.w) + 1.0f);
                            s[q] = fmaf(w4.x, r0, s[q]);
                            s[q] = fmaf(w4.y, r1, s[q]);
                            s[q] = fmaf(w4.z, r2, s[q]);
                            s[q] = fmaf(w4.w, r3, s[q]);
                        }
                    }
                }
#pragma unroll
                for (int q = 0; q < QT; ++q) e[q] = __builtin_amdgcn_exp2f(s[q] * L2E);
            } else {
#pragma unroll
                for (int q = 0; q < QT; ++q) e[q] = 0.f;
            }
            // pack to bf16; sums use rounded values so l matches PV exactly
            unsigned eb[QT];
#pragma unroll
            for (int q = 0; q < QT; ++q) {
                eb[q] = (unsigned)f2b(e[q]);
                sum_q[q] = b2f_lo(eb[q]);
            }
            uint4 u;
            u.x = eb[0] | (eb[1] << 16);
            u.y = eb[2] | (eb[3] << 16);
            u.z = eb[4] | (eb[5] << 16);
            u.w = eb[6] | (eb[7] << 16);
            *(uint4*)&p_l[(size_t)kl * 8] = u;
        }
#pragma unroll
        for (int q = 0; q < QT; ++q) {
            float s = wred_sum(sum_q[q]);
            if ((t & 63) == 0) red_l[q][wid] = s;
        }
    }
    __syncthreads();

    // ---- phase 2: PV, waves split k (row kl handled by wave kl%8) ----
    float4 acc[QT];
#pragma unroll
    for (int q = 0; q < QT; ++q) acc[q] = make_float4(0.f, 0.f, 0.f, 0.f);

    const float* Vb = values + ((size_t)b * NK + kstart) * ND;
#pragma unroll 2
    for (int kl = wid; kl < range8; kl += 8) {
        uint4 u = *(const uint4*)&p_l[(size_t)kl * 8];   // 1 b128 = all 8 bf16 p's
        float pr0 = b2f_lo(u.x), pr1 = b2f_hi(u.x);
        float pr2 = b2f_lo(u.y), pr3 = b2f_hi(u.y);
        float pr4 = b2f_lo(u.z), pr5 = b2f_hi(u.z);
        float pr6 = b2f_lo(u.w), pr7 = b2f_hi(u.w);
        float4 v = *(const float4*)(Vb + (size_t)kl * ND + dl);  // coalesced 1KB
        acc[0].x = fmaf(pr0, v.x, acc[0].x); acc[0].y = fmaf(pr0, v.y, acc[0].y);
        acc[0].z = fmaf(pr0, v.z, acc[0].z); acc[0].w = fmaf(pr0, v.w, acc[0].w);
        acc[1].x = fmaf(pr1, v.x, acc[1].x); acc[1].y = fmaf(pr1, v.y, acc[1].y);
        acc[1].z = fmaf(pr1, v.z, acc[1].z); acc[1].w = fmaf(pr1, v.w, acc[1].w);
        acc[2].x = fmaf(pr2, v.x, acc[2].x); acc[2].y = fmaf(pr2, v.y, acc[2].y);
        acc[2].z = fmaf(pr2, v.z, acc[2].z); acc[2].w = fmaf(pr2, v.w, acc[2].w);
        acc[3].x = fmaf(pr3, v.x, acc[3].x); acc[3].y = fmaf(pr3, v.y, acc[3].y);
        acc[3].z = fmaf(pr3, v.z, acc[3].z); acc[3].w = fmaf(pr3, v.w, acc[3].w);
        acc[4].x = fmaf(pr4, v.x, acc[4].x); acc[4].y = fmaf(pr4, v.y, acc[4].y);
        acc[4].z = fmaf(pr4, v.z, acc[4].z); acc[4].w = fmaf(pr4, v.w, acc[4].w);
        acc[5].x = fmaf(pr5, v.x, acc[5].x); acc[5].y = fmaf(pr5, v.y, acc[5].y);
        acc[5].z = fmaf(pr5, v.z, acc[5].z); acc[5].w = fmaf(pr5, v.w, acc[5].w);
        acc[6].x = fmaf(pr6, v.x, acc[6].x); acc[6].y = fmaf(pr6, v.y, acc[6].y);
        acc[6].z = fmaf(pr6, v.z, acc[6].z); acc[6].w = fmaf(pr6, v.w, acc[6].w);
        acc[7].x = fmaf(pr7, v.x, acc[7].x); acc[7].y = fmaf(pr7, v.y, acc[7].y);
        acc[7].z = fmaf(pr7, v.z, acc[7].z); acc[7].w = fmaf(pr7, v.w, acc[7].w);
    }
    __syncthreads();                          // p-values dead -> reuse buf as scratch

    // ---- phase 3: tree-reduce partials across waves (8 -> 4 -> 2 -> 1) ----
    if (wid >= 4) {
        float* s = buf + (size_t)(wid - 4) * 2048;
#pragma unroll
        for (int q = 0; q < QT; ++q) *(float4*)(s + q * 256 + dl) = acc[q];
    }
    __syncthreads();
    if (wid < 4) {
        const float* s = buf + (size_t)wid * 2048;
#pragma unroll
        for (int q = 0; q < QT; ++q) {
            float4 r = *(const float4*)(s + q * 256 + dl);
            acc[q].x += r.x; acc[q].y += r.y; acc[q].z += r.z; acc[q].w += r.w;
        }
    }
    __syncthreads();
    if (wid >= 2 && wid < 4) {
        float* s = buf + (size_t)(wid - 2) * 2048;
#pragma unroll
        for (int q = 0; q < QT; ++q) *(float4*)(s + q * 256 + dl) = acc[q];
    }
    __syncthreads();
    if (wid < 2) {
        const float* s = buf + (size_t)wid * 2048;
#pragma unroll
        for (int q = 0; q < QT; ++q) {
            float4 r = *(const float4*)(s + q * 256 + dl);
            acc[q].x += r.x; acc[q].y += r.y; acc[q].z += r.z; acc[q].w += r.w;
        }
    }
    __syncthreads();
    if (wid == 1) {
#pragma unroll
        for (int q = 0; q < QT; ++q) *(float4*)(buf + q * 256 + dl) = acc[q];
    }
    __syncthreads();
    if (wid == 0) {
#pragma unroll
        for (int q = 0; q < QT; ++q) {
            float4 r = *(const float4*)(buf + q * 256 + dl);
            acc[q].x += r.x; acc[q].y += r.y; acc[q].z += r.z; acc[q].w += r.w;
            const size_t row4 = ((size_t)(b * NQ + q0 + q) * KSPLIT + sp);
            *(float4*)(po + row4 * ND + dl) = acc[q];
        }
        if (t < QT) {
            float l = 0.f;
#pragma unroll
            for (int i = 0; i < 8; ++i) l += red_l[t][i];
            pml[((size_t)(b * NQ + q0 + t) * KSPLIT + sp)] = l;
        }
    }
}

// ---------- kernel C: combine the four splits ----------
__global__ __launch_bounds__(256) void combine_kernel(
    const float* __restrict__ po, const float* __restrict__ pml,
    float* __restrict__ out)
{
    const int t = threadIdx.x;
    const int row = blockIdx.x * 4 + (t >> 6);
    const int dl = (t & 63) * 4;
    float l = 0.f;
#pragma unroll
    for (int s = 0; s < KSPLIT; ++s) l += pml[row * KSPLIT + s];
    float4 o = make_float4(0.f, 0.f, 0.f, 0.f);
#pragma unroll
    for (int s = 0; s < KSPLIT; ++s) {
        float4 p = *(const float4*)(po + ((size_t)row * KSPLIT + s) * ND + dl);
        o.x += p.x; o.y += p.y; o.z += p.z; o.w += p.w;
    }
    const float inv = 1.0f / l;
    o.x *= inv; o.y *= inv; o.z *= inv; o.w *= inv;
    *(float4*)(out + (size_t)row * ND + dl) = o;
}

extern "C" void kernel_launch(void* const* d_in, const int* in_sizes, int n_in,
                              void* d_out, int out_size, void* d_ws, size_t ws_size,
                              hipStream_t stream) {
    const float* queries   = (const float*)d_in[0];
    const float* keys      = (const float*)d_in[1];
    const float* values    = (const float*)d_in[2];
    const int* valid_lens  = (const int*)d_in[3];
    const float* Wq        = (const float*)d_in[4];
    const float* Wk        = (const float*)d_in[5];
    const float* wv        = (const float*)d_in[6];
    float* out = (float*)d_out;

    float* qp   = (float*)d_ws;                         // NB*NQ*NH      (0.5 MB)
    float4* kp4 = (float4*)(qp + (size_t)NB * NQ * NH); // NB*16*NK f4   (2 MB)
    float* po   = (float*)(kp4 + (size_t)NB * 16 * NK); // NB*NQ*4*ND    (8 MB)
    float* pml  = po + (size_t)NB * NQ * KSPLIT * ND;   // NB*NQ*4

    proj_kernel<<<(NB * NQ + NB * NK) / 16, 256, 0, stream>>>(queries, keys, Wq, Wk, qp, kp4);
    attn_part<<<NB * (NQ / QT) * KSPLIT, 512, 0, stream>>>(values, valid_lens, wv, qp, kp4, po, pml);
    combine_kernel<<<NB * NQ / 4, 256, 0, stream>>>(po, pml, out);
}

// Round 15
// 63.439 us; speedup vs baseline: 1.3269x; 1.2122x over previous
//
#include <hip/hip_runtime.h>
#include <hip/hip_bf16.h>

#define NB 4
#define NQ 512
#define NK 2048
#define ND 256
#define NH 64
#define QT 8                      // queries per attn block
#define KSPLIT 4

#define SCALE_C 2.8853900817779268f   // 2*log2(e): exp2(C*x) = e^{2x}
#define L2E     1.4426950408889634f

__device__ __forceinline__ unsigned short f2b(float f) {   // f32 -> bf16 (RNE)
    unsigned u = __float_as_uint(f);
    u += 0x7fffu + ((u >> 16) & 1u);
    return (unsigned short)(u >> 16);
}
__device__ __forceinline__ float b2f_lo(unsigned u) { return __uint_as_float(u << 16); }
__device__ __forceinline__ float b2f_hi(unsigned u) { return __uint_as_float(u & 0xffff0000u); }

__device__ __forceinline__ float wred_sum(float v) {
#pragma unroll
    for (int off = 32; off; off >>= 1) v += __shfl_xor(v, off, 64);
    return v;
}

// ---------- kernel A: projections -> EXPONENTIALS of 2x the projection ----------
// queries -> EQ[b*NQ+q][h] = e^{2 q.Wq[h]}   (row-major)
// keys    -> EK4[(b*16 + h/4)*NK + k] : float4 h-quad of e^{2 k.Wk[h]}
__global__ __launch_bounds__(256) void proj_kernel(
    const float* __restrict__ queries, const float* __restrict__ keys,
    const float* __restrict__ Wq, const float* __restrict__ Wk,
    float* __restrict__ eq, float4* __restrict__ ek4)
{
    __shared__ __align__(16) float in_lds[16][256];   // 16 KB; reused as [16][64] out
    const int t = threadIdx.x;
    const int row0 = blockIdx.x * 16;
    const bool isQ = row0 < NB * NQ;                  // blocks are purely Q or purely K
    const float* src = isQ ? (queries + (size_t)row0 * ND)
                           : (keys + (size_t)(row0 - NB * NQ) * ND);
    const float* W = isQ ? Wq : Wk;

    const float4* src4 = (const float4*)src;
#pragma unroll
    for (int i = 0; i < 4; ++i) {
        int f4 = t + 256 * i;
        ((float4*)&in_lds[0][0])[f4] = src4[f4];
    }
    __syncthreads();

    const int w = t >> 6, h = t & 63;
    const int r0 = w * 4;
    float a[4] = {0.f, 0.f, 0.f, 0.f};
#pragma unroll 4
    for (int d4 = 0; d4 < 64; ++d4) {
        const float* Wp = W + (size_t)(d4 * 4) * NH + h;
        float w0 = Wp[0], w1 = Wp[NH], w2 = Wp[2 * NH], w3 = Wp[3 * NH];
#pragma unroll
        for (int i = 0; i < 4; ++i) {
            float4 x = ((const float4*)in_lds[r0 + i])[d4];
            a[i] = fmaf(x.x, w0, fmaf(x.y, w1, fmaf(x.z, w2, fmaf(x.w, w3, a[i]))));
        }
    }
    if (isQ) {
#pragma unroll
        for (int i = 0; i < 4; ++i)
            eq[(size_t)(row0 + r0 + i) * NH + h] =
                __builtin_amdgcn_exp2f(a[i] * SCALE_C);
    } else {
        // transpose through LDS to emit h-quads per key
        __syncthreads();                              // in_lds reads complete
        float* out2 = &in_lds[0][0];                  // [16][64]
#pragma unroll
        for (int i = 0; i < 4; ++i)
            out2[(r0 + i) * 64 + h] = __builtin_amdgcn_exp2f(a[i] * SCALE_C);
        __syncthreads();
        const int row = t >> 4, hb = t & 15;          // 16 rows x 16 h-quads
        float4 v = *(const float4*)&out2[row * 64 + hb * 4];
        int kr = row0 - NB * NQ + row;
        int b = kr >> 11, k = kr & (NK - 1);
        ek4[((size_t)(b * 16 + hb)) * NK + k] = v;
    }
}

// ---------- kernel B: partial scores + no-max softmax + partial PV ----------
// grid = NB*(NQ/QT)*KSPLIT = 1024 blocks, 512 threads (8 waves).
// Block decode (diagonal batch<->split pairing): g = n&255, sp = n>>8,
//   b = ((g>>6)+sp)&3, qt = g&63.
// Balanced dynamic split (R8 formula): range <= 512, multiple of 8; phase 1
// straight-line one-k-per-thread. Score inner loop uses the factored form
//   1/(1+e^{2(q+k)}) = rcp( fma(EQ, EK, 1.0) )   -> 2 VALU + 1 trans / element
__global__ __launch_bounds__(512, 8) void attn_part(
    const float* __restrict__ values, const int* __restrict__ valid_lens,
    const float* __restrict__ wv,
    const float* __restrict__ eq, const float4* __restrict__ ek4,
    float* __restrict__ po, float* __restrict__ pml)
{
    __shared__ __align__(16) float qp_l[QT][NH];      // 2 KB (EQ tile, LDS broadcast)
    __shared__ __align__(16) float wv2_l[NH];         // -2*wv
    __shared__ float sumwv_l;
    __shared__ __align__(16) float buf[8192];         // 32 KB: p bf16 (8KB) / red scratch
    __shared__ float red_l[QT][8];

    unsigned short* p_l = (unsigned short*)buf;       // p_l[kl*8 + q], bf16

    const int t = threadIdx.x;
    const int n = blockIdx.x;
    const int g = n & 255;
    const int sp = n >> 8;
    const int b  = ((g >> 6) + sp) & 3;
    const int qt = g & 63;
    const int q0 = qt * QT;
    const int wid = t >> 6;
    const int dl = (t & 63) * 4;

    if (t < 128) {
        int q = t >> 4, h4 = t & 15;
        ((float4*)qp_l[q])[h4] =
            ((const float4*)(eq + (size_t)(b * NQ + q0 + q) * NH))[h4];
    }
    if (t < 64) {
        float wvv = wv[t];
        wv2_l[t] = -2.0f * wvv;
        float s = wred_sum(wvv);
        if (t == 0) sumwv_l = s;
    }
    int vl = valid_lens[b];
    const int kv = vl < 0 ? 0 : (vl > NK ? NK : vl);
    const int kveff = (kv == 0) ? NK : kv;    // kv==0 -> uniform over all keys
    // balanced bounds, range always multiple of 8 and <= 512
    const int step   = ((kveff + 31) & ~31) >> 2;        // ceil(kveff/4) to mult-of-8
    const int kvr8   = (kveff + 7) & ~7;
    const int kstart = sp * step;
    int kend = kstart + step; if (kend > kvr8) kend = kvr8;
    const int range8 = (kend > kstart) ? (kend - kstart) : 0;   // <= 512
    __syncthreads();
    const float sumwv = sumwv_l;

    // ---- phase 1: e-values (bf16) into p_l, ONE k per thread ----
    {
        const int kl = t;
        float sum_q[QT];
#pragma unroll
        for (int q = 0; q < QT; ++q) sum_q[q] = 0.f;
        if (kl < range8) {
            const int kg = kstart + kl;
            float e[QT];
            if (kv == 0) {
#pragma unroll
                for (int q = 0; q < QT; ++q) e[q] = 1.0f;
            } else if (kg < kv) {
                float s[QT];
#pragma unroll
                for (int q = 0; q < QT; ++q) s[q] = sumwv;
                const float4* kT4 = ek4 + (size_t)(b * 16) * NK + kg;  // h-quad stride NK
#pragma unroll
                for (int gq = 0; gq < 4; ++gq) {      // 4 batches of 4 h-quads
                    float4 kb[4];                     // 4 dwordx4 in flight
#pragma unroll
                    for (int i = 0; i < 4; ++i)
                        kb[i] = kT4[(size_t)(gq * 4 + i) * NK];
#pragma unroll
                    for (int i = 0; i < 4; ++i) {
                        const int h4 = gq * 4 + i;
                        float4 w4 = ((const float4*)wv2_l)[h4];
                        float4 kh = kb[i];
#pragma unroll
                        for (int q = 0; q < QT; ++q) {
                            float4 qh = ((const float4*)qp_l[q])[h4];   // LDS broadcast
                            // 1/(1+EQ*EK): fma + rcp + fma  (2 VALU + 1 trans)
                            float r0 = __builtin_amdgcn_rcpf(fmaf(qh.x, kh.x, 1.0f));
                            float r1 = __builtin_amdgcn_rcpf(fmaf(qh.y, kh.y, 1.0f));
                            float r2 = __builtin_amdgcn_rcpf(fmaf(qh.z, kh.z, 1.0f));
                            float r3 = __builtin_amdgcn_rcpf(fmaf(qh.w, kh.w, 1.0f));
                            s[q] = fmaf(w4.x, r0, s[q]);
                            s[q] = fmaf(w4.y, r1, s[q]);
                            s[q] = fmaf(w4.z, r2, s[q]);
                            s[q] = fmaf(w4.w, r3, s[q]);
                        }
                    }
                }
#pragma unroll
                for (int q = 0; q < QT; ++q) e[q] = __builtin_amdgcn_exp2f(s[q] * L2E);
            } else {
#pragma unroll
                for (int q = 0; q < QT; ++q) e[q] = 0.f;
            }
            // pack to bf16; sums use rounded values so l matches PV exactly
            unsigned eb[QT];
#pragma unroll
            for (int q = 0; q < QT; ++q) {
                eb[q] = (unsigned)f2b(e[q]);
                sum_q[q] = b2f_lo(eb[q]);
            }
            uint4 u;
            u.x = eb[0] | (eb[1] << 16);
            u.y = eb[2] | (eb[3] << 16);
            u.z = eb[4] | (eb[5] << 16);
            u.w = eb[6] | (eb[7] << 16);
            *(uint4*)&p_l[(size_t)kl * 8] = u;
        }
#pragma unroll
        for (int q = 0; q < QT; ++q) {
            float s = wred_sum(sum_q[q]);
            if ((t & 63) == 0) red_l[q][wid] = s;
        }
    }
    __syncthreads();

    // ---- phase 2: PV, waves split k (row kl handled by wave kl%8) ----
    float4 acc[QT];
#pragma unroll
    for (int q = 0; q < QT; ++q) acc[q] = make_float4(0.f, 0.f, 0.f, 0.f);

    const float* Vb = values + ((size_t)b * NK + kstart) * ND;
#pragma unroll 2
    for (int kl = wid; kl < range8; kl += 8) {
        uint4 u = *(const uint4*)&p_l[(size_t)kl * 8];   // 1 b128 = all 8 bf16 p's
        float pr0 = b2f_lo(u.x), pr1 = b2f_hi(u.x);
        float pr2 = b2f_lo(u.y), pr3 = b2f_hi(u.y);
        float pr4 = b2f_lo(u.z), pr5 = b2f_hi(u.z);
        float pr6 = b2f_lo(u.w), pr7 = b2f_hi(u.w);
        float4 v = *(const float4*)(Vb + (size_t)kl * ND + dl);  // coalesced 1KB
        acc[0].x = fmaf(pr0, v.x, acc[0].x); acc[0].y = fmaf(pr0, v.y, acc[0].y);
        acc[0].z = fmaf(pr0, v.z, acc[0].z); acc[0].w = fmaf(pr0, v.w, acc[0].w);
        acc[1].x = fmaf(pr1, v.x, acc[1].x); acc[1].y = fmaf(pr1, v.y, acc[1].y);
        acc[1].z = fmaf(pr1, v.z, acc[1].z); acc[1].w = fmaf(pr1, v.w, acc[1].w);
        acc[2].x = fmaf(pr2, v.x, acc[2].x); acc[2].y = fmaf(pr2, v.y, acc[2].y);
        acc[2].z = fmaf(pr2, v.z, acc[2].z); acc[2].w = fmaf(pr2, v.w, acc[2].w);
        acc[3].x = fmaf(pr3, v.x, acc[3].x); acc[3].y = fmaf(pr3, v.y, acc[3].y);
        acc[3].z = fmaf(pr3, v.z, acc[3].z); acc[3].w = fmaf(pr3, v.w, acc[3].w);
        acc[4].x = fmaf(pr4, v.x, acc[4].x); acc[4].y = fmaf(pr4, v.y, acc[4].y);
        acc[4].z = fmaf(pr4, v.z, acc[4].z); acc[4].w = fmaf(pr4, v.w, acc[4].w);
        acc[5].x = fmaf(pr5, v.x, acc[5].x); acc[5].y = fmaf(pr5, v.y, acc[5].y);
        acc[5].z = fmaf(pr5, v.z, acc[5].z); acc[5].w = fmaf(pr5, v.w, acc[5].w);
        acc[6].x = fmaf(pr6, v.x, acc[6].x); acc[6].y = fmaf(pr6, v.y, acc[6].y);
        acc[6].z = fmaf(pr6, v.z, acc[6].z); acc[6].w = fmaf(pr6, v.w, acc[6].w);
        acc[7].x = fmaf(pr7, v.x, acc[7].x); acc[7].y = fmaf(pr7, v.y, acc[7].y);
        acc[7].z = fmaf(pr7, v.z, acc[7].z); acc[7].w = fmaf(pr7, v.w, acc[7].w);
    }
    __syncthreads();                          // p-values dead -> reuse buf as scratch

    // ---- phase 3: tree-reduce partials across waves (8 -> 4 -> 2 -> 1) ----
    if (wid >= 4) {
        float* s = buf + (size_t)(wid - 4) * 2048;
#pragma unroll
        for (int q = 0; q < QT; ++q) *(float4*)(s + q * 256 + dl) = acc[q];
    }
    __syncthreads();
    if (wid < 4) {
        const float* s = buf + (size_t)wid * 2048;
#pragma unroll
        for (int q = 0; q < QT; ++q) {
            float4 r = *(const float4*)(s + q * 256 + dl);
            acc[q].x += r.x; acc[q].y += r.y; acc[q].z += r.z; acc[q].w += r.w;
        }
    }
    __syncthreads();
    if (wid >= 2 && wid < 4) {
        float* s = buf + (size_t)(wid - 2) * 2048;
#pragma unroll
        for (int q = 0; q < QT; ++q) *(float4*)(s + q * 256 + dl) = acc[q];
    }
    __syncthreads();
    if (wid < 2) {
        const float* s = buf + (size_t)wid * 2048;
#pragma unroll
        for (int q = 0; q < QT; ++q) {
            float4 r = *(const float4*)(s + q * 256 + dl);
            acc[q].x += r.x; acc[q].y += r.y; acc[q].z += r.z; acc[q].w += r.w;
        }
    }
    __syncthreads();
    if (wid == 1) {
#pragma unroll
        for (int q = 0; q < QT; ++q) *(float4*)(buf + q * 256 + dl) = acc[q];
    }
    __syncthreads();
    if (wid == 0) {
#pragma unroll
        for (int q = 0; q < QT; ++q) {
            float4 r = *(const float4*)(buf + q * 256 + dl);
            acc[q].x += r.x; acc[q].y += r.y; acc[q].z += r.z; acc[q].w += r.w;
            const size_t row4 = ((size_t)(b * NQ + q0 + q) * KSPLIT + sp);
            *(float4*)(po + row4 * ND + dl) = acc[q];
        }
        if (t < QT) {
            float l = 0.f;
#pragma unroll
            for (int i = 0; i < 8; ++i) l += red_l[t][i];
            pml[((size_t)(b * NQ + q0 + t) * KSPLIT + sp)] = l;
        }
    }
}

// ---------- kernel C: combine the four splits ----------
__global__ __launch_bounds__(256) void combine_kernel(
    const float* __restrict__ po, const float* __restrict__ pml,
    float* __restrict__ out)
{
    const int t = threadIdx.x;
    const int row = blockIdx.x * 4 + (t >> 6);
    const int dl = (t & 63) * 4;
    float l = 0.f;
#pragma unroll
    for (int s = 0; s < KSPLIT; ++s) l += pml[row * KSPLIT + s];
    float4 o = make_float4(0.f, 0.f, 0.f, 0.f);
#pragma unroll
    for (int s = 0; s < KSPLIT; ++s) {
        float4 p = *(const float4*)(po + ((size_t)row * KSPLIT + s) * ND + dl);
        o.x += p.x; o.y += p.y; o.z += p.z; o.w += p.w;
    }
    const float inv = 1.0f / l;
    o.x *= inv; o.y *= inv; o.z *= inv; o.w *= inv;
    *(float4*)(out + (size_t)row * ND + dl) = o;
}

extern "C" void kernel_launch(void* const* d_in, const int* in_sizes, int n_in,
                              void* d_out, int out_size, void* d_ws, size_t ws_size,
                              hipStream_t stream) {
    const float* queries   = (const float*)d_in[0];
    const float* keys      = (const float*)d_in[1];
    const float* values    = (const float*)d_in[2];
    const int* valid_lens  = (const int*)d_in[3];
    const float* Wq        = (const float*)d_in[4];
    const float* Wk        = (const float*)d_in[5];
    const float* wv        = (const float*)d_in[6];
    float* out = (float*)d_out;

    float* eq   = (float*)d_ws;                         // NB*NQ*NH      (0.5 MB)
    float4* ek4 = (float4*)(eq + (size_t)NB * NQ * NH); // NB*16*NK f4   (2 MB)
    float* po   = (float*)(ek4 + (size_t)NB * 16 * NK); // NB*NQ*4*ND    (8 MB)
    float* pml  = po + (size_t)NB * NQ * KSPLIT * ND;   // NB*NQ*4

    proj_kernel<<<(NB * NQ + NB * NK) / 16, 256, 0, stream>>>(queries, keys, Wq, Wk, eq, ek4);
    attn_part<<<NB * (NQ / QT) * KSPLIT, 512, 0, stream>>>(values, valid_lens, wv, eq, ek4, po, pml);
    combine_kernel<<<NB * NQ / 4, 256, 0, stream>>>(po, pml, out);
}